// Round 3
// baseline (591.731 us; speedup 1.0000x reference)
//
#include <hip/hip_runtime.h>
#include <hip/hip_bf16.h>

// out[M,N] = data[M,K] @ (mask*weight)[N,K]^T + bias[N];  M=8192, N=K=4096, fp32.
// R4 (resubmit; R2's bench was lost to a container/infra failure - ledger
// re-audited, no hang path found): same 256x256/BK=64/8-wave tile as R3, but
// LDS reorganized from 2 full-tile buffers into a RING OF 4 HALF-TILE SLOTS
// (32KB each, same 128KiB total). Each half (A-half 128x64 + B-half 128x64)
// is staged as early as its slot frees -> every global_load_lds has 5-6
// phases (~3000 cyc) in flight before its covering vmcnt wait (was ~1.5
// phases ~900 cyc = exposed HBM latency, the measured 45% MfmaUtil gap in R3).
// Waits: vmcnt(10)/(8)/(8) at p0/p1/p2, 16 loads max outstanding, never
// drained in main loop (T4). One barrier per phase; 2 peeled tail tiles with
// exact drain counts. T1 XCD swizzle, T2 XOR-swizzle (conflicts=0), T5 setprio.

#define Mdim 8192
#define Ndim 4096
#define Kdim 4096

typedef __bf16 bf16x8 __attribute__((ext_vector_type(8)));
typedef float f32x4 __attribute__((ext_vector_type(4)));

__device__ inline unsigned short f2bf(float f) {
    union { float f; unsigned u; } v;
    v.f = f;
    unsigned r = v.u + 0x7fffu + ((v.u >> 16) & 1u);
    return (unsigned short)(r >> 16);
}

__device__ inline unsigned pack2(float a, float b) {
    return (unsigned)f2bf(a) | ((unsigned)f2bf(b) << 16);
}

#define GLOAD_LDS16(gp, lp)                                                     \
    __builtin_amdgcn_global_load_lds((const __attribute__((address_space(1))) void*)(gp), \
                                     (__attribute__((address_space(3))) void*)(lp), 16, 0, 0)

#define VMCNT_I(n)  asm volatile("s_waitcnt vmcnt(" #n ")" ::: "memory")
#define VMCNT(n)    VMCNT_I(n)
#define FENCE()     asm volatile("" ::: "memory")
#define BARRIER()   do { FENCE(); __builtin_amdgcn_s_barrier(); FENCE(); } while (0)

// ---- fused conversion: data->bf16 and (weight*mask)->bf16, 16B I/O (unchanged) ----
__global__ __launch_bounds__(256) void k_cvt_all(const float4* __restrict__ data,
                                                 const float4* __restrict__ weight,
                                                 const float4* __restrict__ mask,
                                                 uint4* __restrict__ Abf,
                                                 uint4* __restrict__ Bbf) {
    const int NA = Mdim * (Kdim / 8);
    const int NB = Ndim * (Kdim / 8);
    const int stride = gridDim.x * blockDim.x;
    for (int i = blockIdx.x * blockDim.x + threadIdx.x; i < NA + NB; i += stride) {
        if (i < NA) {
            const size_t j2 = 2 * (size_t)i;
            float4 v0 = data[j2], v1 = data[j2 + 1];
            uint4 o;
            o.x = pack2(v0.x, v0.y); o.y = pack2(v0.z, v0.w);
            o.z = pack2(v1.x, v1.y); o.w = pack2(v1.z, v1.w);
            Abf[i] = o;
        } else {
            const size_t j = (size_t)(i - NA);
            const size_t j2 = 2 * j;
            float4 w0 = weight[j2], w1 = weight[j2 + 1];
            float4 m0 = mask[j2],   m1 = mask[j2 + 1];
            uint4 o;
            o.x = pack2(w0.x * m0.x, w0.y * m0.y);
            o.y = pack2(w0.z * m0.z, w0.w * m0.w);
            o.z = pack2(w1.x * m1.x, w1.y * m1.y);
            o.w = pack2(w1.z * m1.z, w1.w * m1.w);
            Bbf[j] = o;
        }
    }
}

// ---- bf16 MFMA GEMM: C = A * B^T + bias, 256x256 tile, 4-slot half-tile ring ----
__global__ __launch_bounds__(512, 2) void k_gemm256(const unsigned short* __restrict__ A,
                                                    const unsigned short* __restrict__ B,
                                                    const float* __restrict__ bias,
                                                    float* __restrict__ out) {
    // 4 slots x 32KB. Slot s (ushort base s*16384): A-half [128][64] at +0,
    // B-half [128][64] at +8192. Half h -> slot h&3. Physical col-chunk =
    // logical ^ (localrow&7).
    __shared__ __align__(16) unsigned short sh[4 * 16384];

    const int tid  = threadIdx.x;
    const int lane = tid & 63;
    const int wave = tid >> 6;

    // T1: bijective XCD swizzle, nwg=512
    const int bid = blockIdx.x;
    const int swz = (bid & 7) * 64 + (bid >> 3);
    const int bm  = (swz & 31) * 256;
    const int bn  = (swz >> 5) * 256;

    // staging constants
    const int rrow = lane >> 3;                      // 0..7
    const int scol = ((lane & 7) ^ rrow) * 8;        // pre-swizzled global col
    const int ldsl = lane * 8;                       // linear LDS: lane*16B
    const int w8   = wave * 8;
    const int rbB  = (wave >> 2) * 64 + (wave & 3) * 8;

    const int dstA0 = w8 * 64 + ldsl;                // local rows 0-63 (A region)
    const int dstA1 = (64 + w8) * 64 + ldsl;         // local rows 64-127
    const int dstB0 = 8192 + w8 * 64 + ldsl;         // B region
    const int dstB1 = 8192 + (64 + w8) * 64 + ldsl;

    // fragment-read constants
    const int fr = lane & 15;
    const int kc = lane >> 4;
    const int po = (kc ^ (fr & 7)) * 8;
    const int arow = ((wave >> 2) * 64 + fr) * 64;   // A local-row base (ushorts)
    const int brow = ((wave & 3) * 32 + fr) * 64;    // B local-row base

    // global stage pointers (advance by 64 ushorts per tile after staging)
    const unsigned short* pA0 = A + (size_t)(bm + w8 + rrow) * Kdim + scol;        // even, rows 0-63
    const unsigned short* pA1 = pA0 + (size_t)128 * Kdim;                           // even, rows 128-191
    const unsigned short* pA2 = pA0 + (size_t)64 * Kdim;                            // odd, rows 64-127
    const unsigned short* pA3 = pA0 + (size_t)192 * Kdim;                           // odd, rows 192-255
    const unsigned short* pB0 = B + (size_t)(bn + rbB + rrow) * Kdim + scol;        // even
    const unsigned short* pB1 = pB0 + (size_t)128 * Kdim;
    const unsigned short* pB2 = pB0 + (size_t)32 * Kdim;                            // odd
    const unsigned short* pB3 = pB0 + (size_t)160 * Kdim;

    f32x4 acc[8][4];
#pragma unroll
    for (int i = 0; i < 8; ++i)
#pragma unroll
        for (int j = 0; j < 4; ++j) acc[i][j] = (f32x4){0.f, 0.f, 0.f, 0.f};

    bf16x8 a0[4][2], a1[4][2], b0[2][2], b1[2][2];

#define READ_A4(dst, base) do {                                                  \
    _Pragma("unroll")                                                            \
    for (int _i = 0; _i < 4; ++_i) {                                             \
        dst[_i][0] = *(const bf16x8*)&sh[(base) + _i * 1024 + po];               \
        dst[_i][1] = *(const bf16x8*)&sh[(base) + _i * 1024 + (po ^ 32)];        \
    } } while (0)

#define READ_B2(dst, base) do {                                                  \
    _Pragma("unroll")                                                            \
    for (int _j = 0; _j < 2; ++_j) {                                             \
        dst[_j][0] = *(const bf16x8*)&sh[(base) + _j * 1024 + po];               \
        dst[_j][1] = *(const bf16x8*)&sh[(base) + _j * 1024 + (po ^ 32)];        \
    } } while (0)

#define Q_MFMA(AF, BF, IO, JO) do {                                              \
    __builtin_amdgcn_s_setprio(1);                                               \
    _Pragma("unroll")                                                            \
    for (int _i = 0; _i < 4; ++_i) {                                             \
        _Pragma("unroll")                                                        \
        for (int _j = 0; _j < 2; ++_j) {                                         \
            acc[(IO)+_i][(JO)+_j] = __builtin_amdgcn_mfma_f32_16x16x32_bf16(     \
                AF[_i][0], BF[_j][0], acc[(IO)+_i][(JO)+_j], 0, 0, 0);           \
            acc[(IO)+_i][(JO)+_j] = __builtin_amdgcn_mfma_f32_16x16x32_bf16(     \
                AF[_i][1], BF[_j][1], acc[(IO)+_i][(JO)+_j], 0, 0, 0);           \
        } }                                                                      \
    __builtin_amdgcn_s_setprio(0); } while (0)

    // K-tile body. Phases p0..p3, one barrier each; stages post-barrier.
    // Wait ledger (steady): p0 vmcnt(10) retires A(2t+1); p1 vmcnt(8) retires
    // B(2t+1); p2 vmcnt(8) retires A/B(2t+2) (needed by p3-tail reads).
    // Stage->slot safety: slot's prior readers always lgkm'd one barrier back.
#define KTILE(W0_, W1_, W2_, DOSTAGE, DOTAIL, EB, OB, EB2) do {                  \
    /* p0: quadrant (qm0,qn0) */                                                 \
    VMCNT(W0_); BARRIER();                                                       \
    Q_MFMA(a0, b0, 0, 0);                                                        \
    /* p1: quadrant (qm1,qn0) */                                                 \
    READ_A4(a1, (OB) + arow);                                                    \
    VMCNT(W1_); BARRIER();                                                       \
    if (DOSTAGE) {                                                               \
        GLOAD_LDS16(pA0, sh + (EB) + dstA0);                                     \
        GLOAD_LDS16(pA1, sh + (EB) + dstA1);                                     \
        GLOAD_LDS16(pB0, sh + (EB) + dstB0);                                     \
        GLOAD_LDS16(pB1, sh + (EB) + dstB1);                                     \
    }                                                                            \
    Q_MFMA(a1, b0, 4, 0);                                                        \
    /* p2: quadrant (qm1,qn1) */                                                 \
    READ_B2(b1, (OB) + 8192 + brow);                                             \
    VMCNT(W2_); BARRIER();                                                       \
    if (DOSTAGE) {                                                               \
        GLOAD_LDS16(pA2, sh + (OB) + dstA0);                                     \
        GLOAD_LDS16(pA3, sh + (OB) + dstA1);                                     \
    }                                                                            \
    Q_MFMA(a1, b1, 4, 2);                                                        \
    /* p3: quadrant (qm0,qn1) */                                                 \
    BARRIER();                                                                   \
    if (DOSTAGE) {                                                               \
        GLOAD_LDS16(pB2, sh + (OB) + dstB0);                                     \
        GLOAD_LDS16(pB3, sh + (OB) + dstB1);                                     \
        pA0 += 64; pA1 += 64; pA2 += 64; pA3 += 64;                              \
        pB0 += 64; pB1 += 64; pB2 += 64; pB3 += 64;                              \
    }                                                                            \
    Q_MFMA(a0, b1, 0, 2);                                                        \
    if (DOTAIL) {  /* next tile's even-half fragments; reuses a0/b0 regs */      \
        READ_A4(a0, (EB2) + arow);                                               \
        READ_B2(b0, (EB2) + 8192 + brow);                                        \
    } } while (0)

    // ---- prologue: stage halves 0..3 into slots 0..3 (order A(h) then B(h)) ----
    GLOAD_LDS16(pA0, sh + 0 + dstA0);      GLOAD_LDS16(pA1, sh + 0 + dstA1);       // A(0)
    GLOAD_LDS16(pB0, sh + 0 + dstB0);      GLOAD_LDS16(pB1, sh + 0 + dstB1);       // B(0)
    GLOAD_LDS16(pA2, sh + 16384 + dstA0);  GLOAD_LDS16(pA3, sh + 16384 + dstA1);   // A(1)
    GLOAD_LDS16(pB2, sh + 16384 + dstB0);  GLOAD_LDS16(pB3, sh + 16384 + dstB1);   // B(1)
    GLOAD_LDS16(pA0 + 64, sh + 32768 + dstA0); GLOAD_LDS16(pA1 + 64, sh + 32768 + dstA1); // A(2)
    GLOAD_LDS16(pB0 + 64, sh + 32768 + dstB0); GLOAD_LDS16(pB1 + 64, sh + 32768 + dstB1); // B(2)
    GLOAD_LDS16(pA2 + 64, sh + 49152 + dstA0); GLOAD_LDS16(pA3 + 64, sh + 49152 + dstA1); // A(3)
    GLOAD_LDS16(pB2 + 64, sh + 49152 + dstB0); GLOAD_LDS16(pB3 + 64, sh + 49152 + dstB1); // B(3)
    pA0 += 128; pA1 += 128; pA2 += 128; pA3 += 128;
    pB0 += 128; pB1 += 128; pB2 += 128; pB3 += 128;

    VMCNT(12);   // retire A(0),B(0)
    BARRIER();
    READ_A4(a0, 0 + arow);
    READ_B2(b0, 0 + 8192 + brow);

    // ---- main loop: t = 0..61 (stages halves 2t+4, 2t+5), unrolled x2 ----
    for (int t2 = 0; t2 < 31; ++t2) {
        KTILE(10, 8, 8, true, true, 0,     16384, 32768);   // t even
        KTILE(10, 8, 8, true, true, 32768, 49152, 0);       // t odd
    }
    // ---- peeled tile NT-2 = 62 (even): no stages, drain A/B(126) at p2 ----
    KTILE(10, 8, 4, false, true, 0, 16384, 32768);
    // ---- peeled tile NT-1 = 63 (odd): full drain ----
    KTILE(2, 0, 0, false, false, 32768, 49152, 0);

    // ---- epilogue: C/D layout col=lane&15, row=(lane>>4)*4+reg  [m89/m91] ----
    const int wm = (wave >> 2) * 128;
    const int wn = (wave & 3) * 64;
    const int colb = bn + wn + fr;
    const int rowb = bm + wm + (lane >> 4) * 4;
#pragma unroll
    for (int jg = 0; jg < 4; ++jg) {
        const int col = colb + jg * 16;
        const float bv = bias[col];
#pragma unroll
        for (int ig = 0; ig < 8; ++ig) {
            const int row = rowb + ig * 16;
            float* op = out + (size_t)row * Ndim + col;
#pragma unroll
            for (int r = 0; r < 4; ++r) op[(size_t)r * Ndim] = acc[ig][jg][r] + bv;
        }
    }
#undef KTILE
#undef Q_MFMA
#undef READ_A4
#undef READ_B2
}

// ---- fallback (only if ws too small): naive fp32, correct but slow ----
__global__ void k_naive(const float* __restrict__ A, const float* __restrict__ W,
                        const float* __restrict__ Msk, const float* __restrict__ bias,
                        float* __restrict__ out) {
    int n = blockIdx.x * blockDim.x + threadIdx.x;
    int m = blockIdx.y;
    if (n >= Ndim) return;
    const float* a = A + (size_t)m * Kdim;
    const float* w = W + (size_t)n * Kdim;
    const float* mk = Msk + (size_t)n * Kdim;
    float s = 0.f;
    for (int k = 0; k < Kdim; ++k) s += a[k] * w[k] * mk[k];
    out[(size_t)m * Ndim + n] = s + bias[n];
}

extern "C" void kernel_launch(void* const* d_in, const int* in_sizes, int n_in,
                              void* d_out, int out_size, void* d_ws, size_t ws_size,
                              hipStream_t stream) {
    const float* data   = (const float*)d_in[0];
    const float* weight = (const float*)d_in[1];
    const float* mask   = (const float*)d_in[2];
    const float* bias   = (const float*)d_in[3];
    float* out = (float*)d_out;

    const size_t needA = (size_t)Mdim * Kdim * 2;
    const size_t needB = (size_t)Ndim * Kdim * 2;
    if (ws_size < needA + needB) {
        dim3 g((Ndim + 255) / 256, Mdim);
        k_naive<<<g, 256, 0, stream>>>(data, weight, mask, bias, out);
        return;
    }

    unsigned short* Abf = (unsigned short*)d_ws;
    unsigned short* Bbf = Abf + (size_t)Mdim * Kdim;

    k_cvt_all<<<4096, 256, 0, stream>>>((const float4*)data, (const float4*)weight,
                                        (const float4*)mask, (uint4*)Abf, (uint4*)Bbf);

    k_gemm256<<<dim3(512), dim3(512), 0, stream>>>(Abf, Bbf, bias, out);
}

// Round 5
// 540.892 us; speedup vs baseline: 1.0940x; 1.0940x over previous
//
#include <hip/hip_runtime.h>
#include <hip/hip_bf16.h>

// out[M,N] = data[M,K] @ (mask*weight)[N,K]^T + bias[N];  M=8192, N=K=4096, fp32.
// R5 resubmit (R4 round lost to container infra failure; kernel re-audited:
// uniform barriers, exact vmcnt FIFO ledger 12->14->6->8->10->12, no
// overwrite hazard -> no hang path). Faithful m201 8-phase schedule (the
// verified 1563 TF structure): 2 full 64KB dbufs; per iter (2 K-tiles) 8
// phases, each = {2 global_load_lds pre-barrier, quadrant ds_reads, barrier,
// [lgkm by compiler], setprio+16 MFMA, barrier}. vmcnt(6) ONLY at ph0/ph4
// (retires exactly the tile read next; 3 half-tiles stay in flight). Stage
// order B(u+1)@ph0,1 | A(u+2)@ph2,3 | B(u+2)@ph4,5 | A(u+3)@ph6,7 - each
// slot's last reader is >=1 barrier before overwrite. ph0/ph4 first-quadrant
// reads go POST-barrier (their data retires at that same phase's vmcnt).
// k_cvt_all byte-identical for attribution.

#define Mdim 8192
#define Ndim 4096
#define Kdim 4096

typedef __bf16 bf16x8 __attribute__((ext_vector_type(8)));
typedef float f32x4 __attribute__((ext_vector_type(4)));

__device__ inline unsigned short f2bf(float f) {
    union { float f; unsigned u; } v;
    v.f = f;
    unsigned r = v.u + 0x7fffu + ((v.u >> 16) & 1u);
    return (unsigned short)(r >> 16);
}

__device__ inline unsigned pack2(float a, float b) {
    return (unsigned)f2bf(a) | ((unsigned)f2bf(b) << 16);
}

#define GLOAD_LDS16(gp, lp)                                                     \
    __builtin_amdgcn_global_load_lds((const __attribute__((address_space(1))) void*)(gp), \
                                     (__attribute__((address_space(3))) void*)(lp), 16, 0, 0)

#define VMCNT(n)  asm volatile("s_waitcnt vmcnt(" #n ")" ::: "memory")
#define FENCE()   asm volatile("" ::: "memory")
#define BARRIER() do { FENCE(); __builtin_amdgcn_s_barrier(); FENCE(); } while (0)

// ---- fused conversion: data->bf16 and (weight*mask)->bf16, 16B I/O (unchanged) ----
__global__ __launch_bounds__(256) void k_cvt_all(const float4* __restrict__ data,
                                                 const float4* __restrict__ weight,
                                                 const float4* __restrict__ mask,
                                                 uint4* __restrict__ Abf,
                                                 uint4* __restrict__ Bbf) {
    const int NA = Mdim * (Kdim / 8);
    const int NB = Ndim * (Kdim / 8);
    const int stride = gridDim.x * blockDim.x;
    for (int i = blockIdx.x * blockDim.x + threadIdx.x; i < NA + NB; i += stride) {
        if (i < NA) {
            const size_t j2 = 2 * (size_t)i;
            float4 v0 = data[j2], v1 = data[j2 + 1];
            uint4 o;
            o.x = pack2(v0.x, v0.y); o.y = pack2(v0.z, v0.w);
            o.z = pack2(v1.x, v1.y); o.w = pack2(v1.z, v1.w);
            Abf[i] = o;
        } else {
            const size_t j = (size_t)(i - NA);
            const size_t j2 = 2 * j;
            float4 w0 = weight[j2], w1 = weight[j2 + 1];
            float4 m0 = mask[j2],   m1 = mask[j2 + 1];
            uint4 o;
            o.x = pack2(w0.x * m0.x, w0.y * m0.y);
            o.y = pack2(w0.z * m0.z, w0.w * m0.w);
            o.z = pack2(w1.x * m1.x, w1.y * m1.y);
            o.w = pack2(w1.z * m1.z, w1.w * m1.w);
            Bbf[j] = o;
        }
    }
}

// ---- bf16 MFMA GEMM: C = A*B^T + bias, 256x256, m201 8-phase schedule ----
__global__ __launch_bounds__(512, 2) void k_gemm256(const unsigned short* __restrict__ A,
                                                    const unsigned short* __restrict__ B,
                                                    const float* __restrict__ bias,
                                                    float* __restrict__ out) {
    // dbuf d at d*32768 (ushorts): A[256][64] at +0, B[256][64] at +16384.
    // Physical col-chunk = logical ^ (row&7)  (T2; conflicts measured 0).
    __shared__ __align__(16) unsigned short sh[2 * 32768];
#define DB0 0
#define DB1 32768

    const int tid  = threadIdx.x;
    const int lane = tid & 63;
    const int wave = tid >> 6;

    // T1: bijective XCD swizzle, nwg=512
    const int bid = blockIdx.x;
    const int swz = (bid & 7) * 64 + (bid >> 3);
    const int bm  = (swz & 31) * 256;
    const int bn  = (swz >> 5) * 256;

    // staging: thread covers row srow (0..63) of a 64-row group, phys chunk tid&7
    const int srow = tid >> 3;
    const int scol = ((tid & 7) ^ (srow & 7)) * 8;   // pre-swizzled global col
    const int sdst = tid * 8;                        // linear LDS within group
    const unsigned short* pAg = A + (size_t)(bm + srow) * Kdim + scol;
    const unsigned short* pBg = B + (size_t)(bn + srow) * Kdim + scol;

    // fragment reads
    const int fr = lane & 15;
    const int kc = lane >> 4;
    const int po = (kc ^ (fr & 7)) * 8;              // swizzled chunk (k 0..31)
    const int arow = ((wave >> 2) * 128 + fr) * 64;  // wave's A rows: wm..wm+127
    const int brow = ((wave & 3) * 64 + fr) * 64;    // wave's B rows: wn..wn+63

#define STG_A(db, k0, grow) GLOAD_LDS16(pAg + (size_t)(grow) * Kdim + (k0),      \
                                        sh + (db) + (grow) * 64 + sdst)
#define STG_B(db, k0, grow) GLOAD_LDS16(pBg + (size_t)(grow) * Kdim + (k0),      \
                                        sh + (db) + 16384 + (grow) * 64 + sdst)

    f32x4 acc[8][4];
#pragma unroll
    for (int i = 0; i < 8; ++i)
#pragma unroll
        for (int j = 0; j < 4; ++j) acc[i][j] = (f32x4){0.f, 0.f, 0.f, 0.f};

    bf16x8 a0[4][2], a1[4][2], b0[2][2], b1[2][2];

#define READ_A4(dst, base) do {                                                  \
    _Pragma("unroll")                                                            \
    for (int _i = 0; _i < 4; ++_i) {                                             \
        dst[_i][0] = *(const bf16x8*)&sh[(base) + _i * 1024 + po];               \
        dst[_i][1] = *(const bf16x8*)&sh[(base) + _i * 1024 + (po ^ 32)];        \
    } } while (0)

#define READ_B2(dst, base) do {                                                  \
    _Pragma("unroll")                                                            \
    for (int _j = 0; _j < 2; ++_j) {                                             \
        dst[_j][0] = *(const bf16x8*)&sh[(base) + _j * 1024 + po];               \
        dst[_j][1] = *(const bf16x8*)&sh[(base) + _j * 1024 + (po ^ 32)];        \
    } } while (0)

#define Q_MFMA(AF, BF, IO, JO) do {                                              \
    __builtin_amdgcn_s_setprio(1);                                               \
    _Pragma("unroll")                                                            \
    for (int _i = 0; _i < 4; ++_i) {                                             \
        _Pragma("unroll")                                                        \
        for (int _j = 0; _j < 2; ++_j) {                                         \
            acc[(IO)+_i][(JO)+_j] = __builtin_amdgcn_mfma_f32_16x16x32_bf16(     \
                AF[_i][0], BF[_j][0], acc[(IO)+_i][(JO)+_j], 0, 0, 0);           \
            acc[(IO)+_i][(JO)+_j] = __builtin_amdgcn_mfma_f32_16x16x32_bf16(     \
                AF[_i][1], BF[_j][1], acc[(IO)+_i][(JO)+_j], 0, 0, 0);           \
        } }                                                                      \
    __builtin_amdgcn_s_setprio(0); } while (0)

    // One iter = tiles u=2i (DB0) + u+1 (DB1), phases 0-7.
    // FIFO ledger (2 loads/phase, vmcnt(6) at ph0/ph4 retires 8):
    //  ph0-wait retires A(u),B(u)   -> read at ph0(post-bar)..ph3
    //  ph4-wait retires A(u+1),B(u+1) -> read at ph4(post-bar)..ph7
    // Slot overwrite windows: DB1-B stage ph0,1; DB0-A stage ph2,3;
    // DB0-B stage ph4,5; DB1-A stage ph6,7. All >=1 barrier after last reader.
#define ITER(kb, SB1, SA2, SB2, SA3, W4M) do {                                   \
    /* ph0: Q00(u) */                                                            \
    if (SB1) { STG_B(DB1, (kb)+64, 0);  STG_B(DB1, (kb)+64, 64); }               \
    VMCNT(6); BARRIER();                                                         \
    READ_A4(a0, DB0 + arow); READ_B2(b0, DB0 + 16384 + brow);                    \
    Q_MFMA(a0, b0, 0, 0); BARRIER();                                             \
    /* ph1: Q10(u) */                                                            \
    READ_A4(a1, DB0 + 4096 + arow);                                              \
    if (SB1) { STG_B(DB1, (kb)+64, 128); STG_B(DB1, (kb)+64, 192); }             \
    BARRIER(); Q_MFMA(a1, b0, 4, 0); BARRIER();                                  \
    /* ph2: Q11(u) */                                                            \
    READ_B2(b1, DB0 + 16384 + 2048 + brow);                                      \
    if (SA2) { STG_A(DB0, (kb)+128, 0);  STG_A(DB0, (kb)+128, 64); }             \
    BARRIER(); Q_MFMA(a1, b1, 4, 2); BARRIER();                                  \
    /* ph3: Q01(u) */                                                            \
    if (SA2) { STG_A(DB0, (kb)+128, 128); STG_A(DB0, (kb)+128, 192); }           \
    BARRIER(); Q_MFMA(a0, b1, 0, 2); BARRIER();                                  \
    /* ph4: Q00(u+1) */                                                          \
    if (SB2) { STG_B(DB0, (kb)+128, 0);  STG_B(DB0, (kb)+128, 64); }             \
    W4M; BARRIER();                                                              \
    READ_A4(a0, DB1 + arow); READ_B2(b0, DB1 + 16384 + brow);                    \
    Q_MFMA(a0, b0, 0, 0); BARRIER();                                             \
    /* ph5: Q10(u+1) */                                                          \
    READ_A4(a1, DB1 + 4096 + arow);                                              \
    if (SB2) { STG_B(DB0, (kb)+128, 128); STG_B(DB0, (kb)+128, 192); }           \
    BARRIER(); Q_MFMA(a1, b0, 4, 0); BARRIER();                                  \
    /* ph6: Q11(u+1) */                                                          \
    READ_B2(b1, DB1 + 16384 + 2048 + brow);                                      \
    if (SA3) { STG_A(DB1, (kb)+192, 0);  STG_A(DB1, (kb)+192, 64); }             \
    BARRIER(); Q_MFMA(a1, b1, 4, 2); BARRIER();                                  \
    /* ph7: Q01(u+1) */                                                          \
    if (SA3) { STG_A(DB1, (kb)+192, 128); STG_A(DB1, (kb)+192, 192); }           \
    BARRIER(); Q_MFMA(a0, b1, 0, 2); BARRIER();                                  \
} while (0)

    // ---- prologue: A(0),B(0) -> DB0; A(1) -> DB1-A  (12 loads, FIFO order) ----
    STG_A(DB0, 0, 0);  STG_A(DB0, 0, 64);  STG_A(DB0, 0, 128);  STG_A(DB0, 0, 192);
    STG_B(DB0, 0, 0);  STG_B(DB0, 0, 64);  STG_B(DB0, 0, 128);  STG_B(DB0, 0, 192);
    STG_A(DB1, 64, 0); STG_A(DB1, 64, 64); STG_A(DB1, 64, 128); STG_A(DB1, 64, 192);

    // ---- main: iters 0..30 (tiles 0..61; stages through A(63)) ----
    for (int i = 0; i < 31; ++i) {
        const int kb = i * 128;
        ITER(kb, true, true, true, true, VMCNT(6));
    }
    // ---- tail iter 31 (tiles 62,63): stage only B(63); drain at ph4 ----
    ITER(3968, true, false, false, false, VMCNT(0));

    // ---- epilogue: C/D layout col=lane&15, row=(lane>>4)*4+reg  [m89/m91] ----
    const int wm = (wave >> 2) * 128;
    const int wn = (wave & 3) * 64;
    const int colb = bn + wn + fr;
    const int rowb = bm + wm + (lane >> 4) * 4;
#pragma unroll
    for (int jg = 0; jg < 4; ++jg) {
        const int col = colb + jg * 16;
        const float bv = bias[col];
#pragma unroll
        for (int ig = 0; ig < 8; ++ig) {
            const int row = rowb + ig * 16;
            float* op = out + (size_t)row * Ndim + col;
#pragma unroll
            for (int r = 0; r < 4; ++r) op[(size_t)r * Ndim] = acc[ig][jg][r] + bv;
        }
    }
#undef ITER
#undef Q_MFMA
#undef READ_A4
#undef READ_B2
#undef STG_A
#undef STG_B
#undef DB0
#undef DB1
}

// ---- fallback (only if ws too small): naive fp32, correct but slow ----
__global__ void k_naive(const float* __restrict__ A, const float* __restrict__ W,
                        const float* __restrict__ Msk, const float* __restrict__ bias,
                        float* __restrict__ out) {
    int n = blockIdx.x * blockDim.x + threadIdx.x;
    int m = blockIdx.y;
    if (n >= Ndim) return;
    const float* a = A + (size_t)m * Kdim;
    const float* w = W + (size_t)n * Kdim;
    const float* mk = Msk + (size_t)n * Kdim;
    float s = 0.f;
    for (int k = 0; k < Kdim; ++k) s += a[k] * w[k] * mk[k];
    out[(size_t)m * Ndim + n] = s + bias[n];
}

extern "C" void kernel_launch(void* const* d_in, const int* in_sizes, int n_in,
                              void* d_out, int out_size, void* d_ws, size_t ws_size,
                              hipStream_t stream) {
    const float* data   = (const float*)d_in[0];
    const float* weight = (const float*)d_in[1];
    const float* mask   = (const float*)d_in[2];
    const float* bias   = (const float*)d_in[3];
    float* out = (float*)d_out;

    const size_t needA = (size_t)Mdim * Kdim * 2;
    const size_t needB = (size_t)Ndim * Kdim * 2;
    if (ws_size < needA + needB) {
        dim3 g((Ndim + 255) / 256, Mdim);
        k_naive<<<g, 256, 0, stream>>>(data, weight, mask, bias, out);
        return;
    }

    unsigned short* Abf = (unsigned short*)d_ws;
    unsigned short* Bbf = Abf + (size_t)Mdim * Kdim;

    k_cvt_all<<<4096, 256, 0, stream>>>((const float4*)data, (const float4*)weight,
                                        (const float4*)mask, (uint4*)Abf, (uint4*)Bbf);

    k_gemm256<<<dim3(512), dim3(512), 0, stream>>>(Abf, Bbf, bias, out);
}